// Round 19
// baseline (241.985 us; speedup 1.0000x reference)
//
#include <hip/hip_runtime.h>

typedef __bf16 bf16x8 __attribute__((ext_vector_type(8)));
typedef float  f32x4  __attribute__((ext_vector_type(4)));

#define LOG2E 1.4426950408889634f

static __device__ __forceinline__ float fexp2(float x) { return __builtin_amdgcn_exp2f(x); }
static __device__ __forceinline__ float frcp(float x)  { return __builtin_amdgcn_rcpf(x); }
static __device__ __forceinline__ float fsigmoid(float x) { return frcp(1.0f + fexp2(-LOG2E * x)); }
static __device__ __forceinline__ float ftanh(float x)    { return 2.0f * frcp(1.0f + fexp2(-2.0f * LOG2E * x)) - 1.0f; }

// ---------------------------------------------------------------------------
// Prep (verified r10-r18): pack 4 [512x512] fp32 weights into bf16 16x16x32
// B-fragment order, GATE-CONTIGUOUS:
// Wp[(((cn*16+ks)*4+g)*64 + lt)*8 + e] = W_g[cn*16+(lt&15)][ks*32+(lt>>4)*8+e]
// Per (cn,ks): 4 KiB = 4 gates x 1 KiB, lane-linear.
// ---------------------------------------------------------------------------
__global__ __launch_bounds__(256) void wpack(const float* __restrict__ Wf,
                                             const float* __restrict__ Wi,
                                             const float* __restrict__ Wg,
                                             const float* __restrict__ Wo,
                                             __bf16* __restrict__ Wp)
{
    int idx = blockIdx.x * 256 + threadIdx.x;      // [0, 131072)
    int kg  = idx & 63;                            // k-group of 8
    int j   = (idx >> 6) & 511;                    // weight row = output col
    int g   = idx >> 15;
    const float* src = (g == 0) ? Wf : (g == 1) ? Wi : (g == 2) ? Wg : Wo;
    const float4* s4 = (const float4*)(src + j * 512 + kg * 8);
    float4 v0 = s4[0], v1 = s4[1];
    bf16x8 o;
    o[0] = (__bf16)v0.x; o[1] = (__bf16)v0.y; o[2] = (__bf16)v0.z; o[3] = (__bf16)v0.w;
    o[4] = (__bf16)v1.x; o[5] = (__bf16)v1.y; o[6] = (__bf16)v1.z; o[7] = (__bf16)v1.w;
    int cn = j >> 4;                               // 16-col group
    int ks = kg >> 2;                              // K=32 step
    int lt = (j & 15) + (kg & 3) * 16;             // lane slot
    size_t dst = ((size_t)(((cn * 16 + ks) * 4 + g) * 64 + lt)) * 8;
    *(bf16x8*)(Wp + dst) = o;
}

// ---------------------------------------------------------------------------
// Main fused kernel = r5 geometry (BM=64, 64 KiB LDS, 2 blocks/CU, 4 waves/
// SIMD, acc = 4m x 4g x 4 = 64) + r18's compiler-proof 2-deep B pipeline
// (inline-asm global_load_dwordx4 + counted vmcnt(4) + sched_barrier).
// IO overlap is structural: two resident blocks desync, so one block's
// phase-0 HBM streaming and store drains run under the other's K-loop.
// ---------------------------------------------------------------------------
__global__ __launch_bounds__(512, 4) void lstm_main(
    const float* __restrict__ xin, const float* __restrict__ stm,
    const __bf16* __restrict__ Wp,
    const float* __restrict__ bfv, const float* __restrict__ biv,
    const float* __restrict__ bgv, const float* __restrict__ bov,
    float* __restrict__ out)
{
    __shared__ unsigned char zs[65536];            // 64 rows x 512 k, bf16, frag image
    const int tid  = threadIdx.x;
    const int lane = tid & 63;
    const int wv   = tid >> 6;                     // 0..7
    const int l15  = lane & 15;
    const int lq   = lane >> 4;                    // 0..3
    const int row0 = blockIdx.x * 64;

    // ---- phase 0: z = x + stm -> bf16 -> LDS frag image (verified r5) ----
    {
        const float* xb = xin + (size_t)row0 * 512;
        const float* sb = stm + (size_t)row0 * 512;
        #pragma unroll
        for (int it = 0; it < 8; ++it) {
            int idx = it * 512 + tid;              // [0, 4096): 64 rows x 64 kgroups
            int row = idx >> 6;
            int kg  = idx & 63;
            const float4* x4 = (const float4*)(xb + row * 512 + kg * 8);
            const float4* s4 = (const float4*)(sb + row * 512 + kg * 8);
            float4 a0 = x4[0], a1 = x4[1];
            float4 b0 = s4[0], b1 = s4[1];
            bf16x8 p;
            p[0] = (__bf16)(a0.x + b0.x); p[1] = (__bf16)(a0.y + b0.y);
            p[2] = (__bf16)(a0.z + b0.z); p[3] = (__bf16)(a0.w + b0.w);
            p[4] = (__bf16)(a1.x + b1.x); p[5] = (__bf16)(a1.y + b1.y);
            p[6] = (__bf16)(a1.z + b1.z); p[7] = (__bf16)(a1.w + b1.w);
            int rb   = row >> 5;                   // 0..1 chunk (32 KiB each)
            int kk   = kg >> 1;
            int slot = ((row & 31) + (kg & 1) * 32) ^ (kk & 7);
            *(bf16x8*)(zs + rb * 32768 + kk * 1024 + slot * 16) = p;
        }
    }
    __syncthreads();                               // only barrier

    // A-read invariants (verified r5): m = 0..3, row = m*16 + l15:
    // byte = (m>>1)*32768 + (m&1)*256 + ((sl0^kk7)<<4) + ks*2048 + (kkoff<<10)
    const int kkoff = lq >> 1;                     // 0/1
    const int sl0   = l15 + (lq & 1) * 32;         // bit4 clear
    const int koffb = kkoff << 10;

#define LOADB(B0, B1, B2, B3, KS) { \
    const char* a_ = bp + (KS) * 4096; \
    asm volatile("global_load_dwordx4 %0, %4, off\n\t" \
                 "global_load_dwordx4 %1, %4, off offset:1024\n\t" \
                 "global_load_dwordx4 %2, %4, off offset:2048\n\t" \
                 "global_load_dwordx4 %3, %4, off offset:3072" \
                 : "=&v"(B0), "=&v"(B1), "=&v"(B2), "=&v"(B3) : "v"(a_)); }
#define WAITB4 { asm volatile("s_waitcnt vmcnt(4)"); __builtin_amdgcn_sched_barrier(0x107); }
#define WAITB0 { asm volatile("s_waitcnt vmcnt(0)"); __builtin_amdgcn_sched_barrier(0x107); }
#define DOMFMA(B0, B1, B2, B3, KS) { \
    const int kk7_ = ((2 * (KS)) & 7) | kkoff; \
    const int t0_  = ((sl0 ^ kk7_) << 4) + (KS) * 2048 + koffb; \
    bf16x8 a0_ = *(const bf16x8*)(zs + t0_); \
    bf16x8 a1_ = *(const bf16x8*)(zs + t0_ + 256); \
    bf16x8 a2_ = *(const bf16x8*)(zs + 32768 + t0_); \
    bf16x8 a3_ = *(const bf16x8*)(zs + 32768 + t0_ + 256); \
    __builtin_amdgcn_s_setprio(1); \
    acc[0][0] = __builtin_amdgcn_mfma_f32_16x16x32_bf16(a0_, B0, acc[0][0], 0, 0, 0); \
    acc[1][0] = __builtin_amdgcn_mfma_f32_16x16x32_bf16(a1_, B0, acc[1][0], 0, 0, 0); \
    acc[2][0] = __builtin_amdgcn_mfma_f32_16x16x32_bf16(a2_, B0, acc[2][0], 0, 0, 0); \
    acc[3][0] = __builtin_amdgcn_mfma_f32_16x16x32_bf16(a3_, B0, acc[3][0], 0, 0, 0); \
    acc[0][1] = __builtin_amdgcn_mfma_f32_16x16x32_bf16(a0_, B1, acc[0][1], 0, 0, 0); \
    acc[1][1] = __builtin_amdgcn_mfma_f32_16x16x32_bf16(a1_, B1, acc[1][1], 0, 0, 0); \
    acc[2][1] = __builtin_amdgcn_mfma_f32_16x16x32_bf16(a2_, B1, acc[2][1], 0, 0, 0); \
    acc[3][1] = __builtin_amdgcn_mfma_f32_16x16x32_bf16(a3_, B1, acc[3][1], 0, 0, 0); \
    acc[0][2] = __builtin_amdgcn_mfma_f32_16x16x32_bf16(a0_, B2, acc[0][2], 0, 0, 0); \
    acc[1][2] = __builtin_amdgcn_mfma_f32_16x16x32_bf16(a1_, B2, acc[1][2], 0, 0, 0); \
    acc[2][2] = __builtin_amdgcn_mfma_f32_16x16x32_bf16(a2_, B2, acc[2][2], 0, 0, 0); \
    acc[3][2] = __builtin_amdgcn_mfma_f32_16x16x32_bf16(a3_, B2, acc[3][2], 0, 0, 0); \
    acc[0][3] = __builtin_amdgcn_mfma_f32_16x16x32_bf16(a0_, B3, acc[0][3], 0, 0, 0); \
    acc[1][3] = __builtin_amdgcn_mfma_f32_16x16x32_bf16(a1_, B3, acc[1][3], 0, 0, 0); \
    acc[2][3] = __builtin_amdgcn_mfma_f32_16x16x32_bf16(a2_, B3, acc[2][3], 0, 0, 0); \
    acc[3][3] = __builtin_amdgcn_mfma_f32_16x16x32_bf16(a3_, B3, acc[3][3], 0, 0, 0); \
    __builtin_amdgcn_s_setprio(0); }

    // ---- phase 1: column loop, no barriers ----
    for (int ci = 0; ci < 4; ++ci) {
        const int cn   = ci * 8 + wv;              // 16-col group [0,32)
        const int colj = cn * 16 + l15;
        const char* bp = (const char*)Wp + (size_t)cn * 65536 + (size_t)lane * 16;

        float bias0 = bfv[colj], bias1 = biv[colj];
        float bias2 = bgv[colj], bias3 = bov[colj];
        f32x4 acc[4][4];                           // [m][gate] = 64 AGPR
        #pragma unroll
        for (int m = 0; m < 4; ++m) {
            #pragma unroll
            for (int r = 0; r < 4; ++r) {
                acc[m][0][r] = bias0; acc[m][1][r] = bias1;
                acc[m][2][r] = bias2; acc[m][3][r] = bias3;
            }
        }

        bf16x8 P0, P1, P2, P3;                     // B set even-ks
        bf16x8 Q0, Q1, Q2, Q3;                     // B set odd-ks

        // drain prior-ci stores + bias loads so counted waits see only B loads
        asm volatile("s_waitcnt vmcnt(0)");
        __builtin_amdgcn_sched_barrier(0);
        LOADB(P0, P1, P2, P3, 0)
        #pragma unroll
        for (int ks = 0; ks < 16; ++ks) {
            if (ks < 15) {
                if ((ks + 1) & 1) { LOADB(Q0, Q1, Q2, Q3, ks + 1) }
                else              { LOADB(P0, P1, P2, P3, ks + 1) }
                WAITB4
            } else {
                WAITB0
            }
            if (ks & 1) { DOMFMA(Q0, Q1, Q2, Q3, ks) }
            else        { DOMFMA(P0, P1, P2, P3, ks) }
        }

        // ---- epilogue (verified r5): col = l&15, row = lq*4 + r ----
        #pragma unroll
        for (int m = 0; m < 4; ++m) {
            #pragma unroll
            for (int r = 0; r < 4; ++r) {
                float F = acc[m][0][r], I = acc[m][1][r];
                float G = acc[m][2][r], O = acc[m][3][r];
                float c = fsigmoid(F) + fsigmoid(I) * ftanh(G);
                float h = ftanh(c) * fsigmoid(O);
                int row = row0 + m * 16 + lq * 4 + r;
                int o   = row * 512 + colj;
                out[o] = c;
                out[33554432 + o] = h;             // h plane at 65536*512
            }
        }
    }
#undef LOADB
#undef WAITB4
#undef WAITB0
#undef DOMFMA
}

extern "C" void kernel_launch(void* const* d_in, const int* in_sizes, int n_in,
                              void* d_out, int out_size, void* d_ws, size_t ws_size,
                              hipStream_t stream) {
    const float* xin = (const float*)d_in[0];
    const float* stm = (const float*)d_in[1];
    const float* Wf  = (const float*)d_in[2];
    const float* bf_ = (const float*)d_in[3];
    const float* Wi  = (const float*)d_in[4];
    const float* bi_ = (const float*)d_in[5];
    const float* Wg  = (const float*)d_in[6];
    const float* bg_ = (const float*)d_in[7];
    const float* Wo  = (const float*)d_in[8];
    const float* bo_ = (const float*)d_in[9];
    __bf16* Wp = (__bf16*)d_ws;                    // 2 MiB packed weights

    wpack<<<512, 256, 0, stream>>>(Wf, Wi, Wg, Wo, Wp);
    lstm_main<<<1024, 512, 0, stream>>>(xin, stm, Wp, bf_, bi_, bg_, bo_, (float*)d_out);
}

// Round 20
// 176.327 us; speedup vs baseline: 1.3724x; 1.3724x over previous
//
#include <hip/hip_runtime.h>

typedef __bf16 bf16x8 __attribute__((ext_vector_type(8)));
typedef float  f32x4  __attribute__((ext_vector_type(4)));

#define LOG2E 1.4426950408889634f

static __device__ __forceinline__ float fexp2(float x) { return __builtin_amdgcn_exp2f(x); }
static __device__ __forceinline__ float frcp(float x)  { return __builtin_amdgcn_rcpf(x); }
static __device__ __forceinline__ float fsigmoid(float x) { return frcp(1.0f + fexp2(-LOG2E * x)); }
static __device__ __forceinline__ float ftanh(float x)    { return 2.0f * frcp(1.0f + fexp2(-2.0f * LOG2E * x)) - 1.0f; }

// ---------------------------------------------------------------------------
// Prep (verified r10-r19): pack 4 [512x512] fp32 weights into bf16 16x16x32
// B-fragment order, GATE-CONTIGUOUS:
// Wp[(((cn*16+ks)*4+g)*64 + lt)*8 + e] = W_g[cn*16+(lt&15)][ks*32+(lt>>4)*8+e]
// ---------------------------------------------------------------------------
__global__ __launch_bounds__(256) void wpack(const float* __restrict__ Wf,
                                             const float* __restrict__ Wi,
                                             const float* __restrict__ Wg,
                                             const float* __restrict__ Wo,
                                             __bf16* __restrict__ Wp)
{
    int idx = blockIdx.x * 256 + threadIdx.x;      // [0, 131072)
    int kg  = idx & 63;                            // k-group of 8
    int j   = (idx >> 6) & 511;                    // weight row = output col
    int g   = idx >> 15;
    const float* src = (g == 0) ? Wf : (g == 1) ? Wi : (g == 2) ? Wg : Wo;
    const float4* s4 = (const float4*)(src + j * 512 + kg * 8);
    float4 v0 = s4[0], v1 = s4[1];
    bf16x8 o;
    o[0] = (__bf16)v0.x; o[1] = (__bf16)v0.y; o[2] = (__bf16)v0.z; o[3] = (__bf16)v0.w;
    o[4] = (__bf16)v1.x; o[5] = (__bf16)v1.y; o[6] = (__bf16)v1.z; o[7] = (__bf16)v1.w;
    int cn = j >> 4;                               // 16-col group
    int ks = kg >> 2;                              // K=32 step
    int lt = (j & 15) + (kg & 3) * 16;             // lane slot
    size_t dst = ((size_t)(((cn * 16 + ks) * 4 + g) * 64 + lt)) * 8;
    *(bf16x8*)(Wp + dst) = o;
}

// ---------------------------------------------------------------------------
// Main fused kernel = r18 (BM=128, asm 2-deep B pipeline, 183 us) with
// phase-0 FUSED into ci=0 as a k-slice pipeline: slice ks staged (asm loads
// issued 2 slices ahead, counted vmcnt, ds_write + lgkmcnt + raw s_barrier -
// no vmcnt drain, loads stay in flight) right before DOMFMA(ks) consumes it.
// ci=0 is paced by HBM (~50k cyc) with its MFMA hidden inside; ci=1..3 run
// the proven r18 pipeline. 512 thr, 128 KiB LDS, 2 waves/SIMD.
// ---------------------------------------------------------------------------
__global__ __launch_bounds__(512, 2) void lstm_main(
    const float* __restrict__ xin, const float* __restrict__ stm,
    const __bf16* __restrict__ Wp,
    const float* __restrict__ bfv, const float* __restrict__ biv,
    const float* __restrict__ bgv, const float* __restrict__ bov,
    float* __restrict__ out)
{
    __shared__ unsigned char zs[131072];           // 128 rows x 512 k, bf16, frag order
    const int tid  = threadIdx.x;
    const int lane = tid & 63;
    const int wv   = tid >> 6;                     // 0..7
    const int l15  = lane & 15;
    const int lq   = lane >> 4;                    // 0..3
    const int row0 = blockIdx.x * 128;

    // A-read invariants (verified r6/r18):
    const int kkoff = lq >> 1;                     // 0/1
    const int sl0   = l15 + (lq & 1) * 32;         // bit4 clear
    const int koffb = kkoff << 10;

    // staging invariants: thread covers (srow, kg = 4*slice + kgl), 8 k each
    const int srow   = tid >> 2;                   // 0..127
    const int kgl    = tid & 3;
    const int st_kh  = kgl >> 1;
    const int st_r31 = (srow & 31) + (kgl & 1) * 32;
    const int st_cb  = (srow >> 5) * 32768;
    const char* xq = (const char*)xin + ((size_t)(row0 + srow) * 512 + kgl * 8) * 4;
    const char* sq = (const char*)stm + ((size_t)(row0 + srow) * 512 + kgl * 8) * 4;

#define LOADB(B0, B1, B2, B3, KS) { \
    const char* a_ = bp + (KS) * 4096; \
    asm volatile("global_load_dwordx4 %0, %4, off\n\t" \
                 "global_load_dwordx4 %1, %4, off offset:1024\n\t" \
                 "global_load_dwordx4 %2, %4, off offset:2048\n\t" \
                 "global_load_dwordx4 %3, %4, off offset:3072" \
                 : "=&v"(B0), "=&v"(B1), "=&v"(B2), "=&v"(B3) : "v"(a_)); }
#define STLD(X0, X1, S0, S1, J) { \
    const char* xp_ = xq + (J) * 128; \
    const char* sp_ = sq + (J) * 128; \
    asm volatile("global_load_dwordx4 %0, %4, off\n\t" \
                 "global_load_dwordx4 %1, %4, off offset:16\n\t" \
                 "global_load_dwordx4 %2, %5, off\n\t" \
                 "global_load_dwordx4 %3, %5, off offset:16" \
                 : "=&v"(X0), "=&v"(X1), "=&v"(S0), "=&v"(S1) \
                 : "v"(xp_), "v"(sp_)); }
#define STWR(X0, X1, S0, S1, J) { \
    bf16x8 p_; \
    p_[0] = (__bf16)(X0[0] + S0[0]); p_[1] = (__bf16)(X0[1] + S0[1]); \
    p_[2] = (__bf16)(X0[2] + S0[2]); p_[3] = (__bf16)(X0[3] + S0[3]); \
    p_[4] = (__bf16)(X1[0] + S1[0]); p_[5] = (__bf16)(X1[1] + S1[1]); \
    p_[6] = (__bf16)(X1[2] + S1[2]); p_[7] = (__bf16)(X1[3] + S1[3]); \
    const int kk_ = 2 * (J) + st_kh; \
    *(bf16x8*)(zs + st_cb + kk_ * 1024 + ((st_r31 ^ (kk_ & 7)) << 4)) = p_; \
    asm volatile("s_waitcnt lgkmcnt(0)" ::: "memory"); \
    __builtin_amdgcn_s_barrier(); \
    __builtin_amdgcn_sched_barrier(0); }
#define WAITC(N) { asm volatile("s_waitcnt vmcnt(" #N ")"); __builtin_amdgcn_sched_barrier(0); }
#define WAITD(N) { asm volatile("s_waitcnt vmcnt(" #N ")"); __builtin_amdgcn_sched_barrier(0x107); }
#define WAITB4 { asm volatile("s_waitcnt vmcnt(4)"); __builtin_amdgcn_sched_barrier(0x107); }
#define WAITB0 { asm volatile("s_waitcnt vmcnt(0)"); __builtin_amdgcn_sched_barrier(0x107); }
#define DOMFMA(B0, B1, B2, B3, KS) { \
    const int kk7_ = ((2 * (KS)) & 7) | kkoff; \
    const int t0_  = ((sl0 ^ kk7_) << 4) + (KS) * 2048 + koffb; \
    { \
        bf16x8 a0_ = *(const bf16x8*)(zs + t0_); \
        bf16x8 a1_ = *(const bf16x8*)(zs + t0_ + 256); \
        bf16x8 a2_ = *(const bf16x8*)(zs + 32768 + t0_); \
        bf16x8 a3_ = *(const bf16x8*)(zs + 32768 + t0_ + 256); \
        __builtin_amdgcn_s_setprio(1); \
        acc[0][0] = __builtin_amdgcn_mfma_f32_16x16x32_bf16(a0_, B0, acc[0][0], 0, 0, 0); \
        acc[1][0] = __builtin_amdgcn_mfma_f32_16x16x32_bf16(a1_, B0, acc[1][0], 0, 0, 0); \
        acc[2][0] = __builtin_amdgcn_mfma_f32_16x16x32_bf16(a2_, B0, acc[2][0], 0, 0, 0); \
        acc[3][0] = __builtin_amdgcn_mfma_f32_16x16x32_bf16(a3_, B0, acc[3][0], 0, 0, 0); \
        acc[0][1] = __builtin_amdgcn_mfma_f32_16x16x32_bf16(a0_, B1, acc[0][1], 0, 0, 0); \
        acc[1][1] = __builtin_amdgcn_mfma_f32_16x16x32_bf16(a1_, B1, acc[1][1], 0, 0, 0); \
        acc[2][1] = __builtin_amdgcn_mfma_f32_16x16x32_bf16(a2_, B1, acc[2][1], 0, 0, 0); \
        acc[3][1] = __builtin_amdgcn_mfma_f32_16x16x32_bf16(a3_, B1, acc[3][1], 0, 0, 0); \
        acc[0][2] = __builtin_amdgcn_mfma_f32_16x16x32_bf16(a0_, B2, acc[0][2], 0, 0, 0); \
        acc[1][2] = __builtin_amdgcn_mfma_f32_16x16x32_bf16(a1_, B2, acc[1][2], 0, 0, 0); \
        acc[2][2] = __builtin_amdgcn_mfma_f32_16x16x32_bf16(a2_, B2, acc[2][2], 0, 0, 0); \
        acc[3][2] = __builtin_amdgcn_mfma_f32_16x16x32_bf16(a3_, B2, acc[3][2], 0, 0, 0); \
        acc[0][3] = __builtin_amdgcn_mfma_f32_16x16x32_bf16(a0_, B3, acc[0][3], 0, 0, 0); \
        acc[1][3] = __builtin_amdgcn_mfma_f32_16x16x32_bf16(a1_, B3, acc[1][3], 0, 0, 0); \
        acc[2][3] = __builtin_amdgcn_mfma_f32_16x16x32_bf16(a2_, B3, acc[2][3], 0, 0, 0); \
        acc[3][3] = __builtin_amdgcn_mfma_f32_16x16x32_bf16(a3_, B3, acc[3][3], 0, 0, 0); \
        __builtin_amdgcn_s_setprio(0); \
    } \
    { \
        bf16x8 a4_ = *(const bf16x8*)(zs + 65536 + t0_); \
        bf16x8 a5_ = *(const bf16x8*)(zs + 65536 + t0_ + 256); \
        bf16x8 a6_ = *(const bf16x8*)(zs + 98304 + t0_); \
        bf16x8 a7_ = *(const bf16x8*)(zs + 98304 + t0_ + 256); \
        __builtin_amdgcn_s_setprio(1); \
        acc[4][0] = __builtin_amdgcn_mfma_f32_16x16x32_bf16(a4_, B0, acc[4][0], 0, 0, 0); \
        acc[5][0] = __builtin_amdgcn_mfma_f32_16x16x32_bf16(a5_, B0, acc[5][0], 0, 0, 0); \
        acc[6][0] = __builtin_amdgcn_mfma_f32_16x16x32_bf16(a6_, B0, acc[6][0], 0, 0, 0); \
        acc[7][0] = __builtin_amdgcn_mfma_f32_16x16x32_bf16(a7_, B0, acc[7][0], 0, 0, 0); \
        acc[4][1] = __builtin_amdgcn_mfma_f32_16x16x32_bf16(a4_, B1, acc[4][1], 0, 0, 0); \
        acc[5][1] = __builtin_amdgcn_mfma_f32_16x16x32_bf16(a5_, B1, acc[5][1], 0, 0, 0); \
        acc[6][1] = __builtin_amdgcn_mfma_f32_16x16x32_bf16(a6_, B1, acc[6][1], 0, 0, 0); \
        acc[7][1] = __builtin_amdgcn_mfma_f32_16x16x32_bf16(a7_, B1, acc[7][1], 0, 0, 0); \
        acc[4][2] = __builtin_amdgcn_mfma_f32_16x16x32_bf16(a4_, B2, acc[4][2], 0, 0, 0); \
        acc[5][2] = __builtin_amdgcn_mfma_f32_16x16x32_bf16(a5_, B2, acc[5][2], 0, 0, 0); \
        acc[6][2] = __builtin_amdgcn_mfma_f32_16x16x32_bf16(a6_, B2, acc[6][2], 0, 0, 0); \
        acc[7][2] = __builtin_amdgcn_mfma_f32_16x16x32_bf16(a7_, B2, acc[7][2], 0, 0, 0); \
        acc[4][3] = __builtin_amdgcn_mfma_f32_16x16x32_bf16(a4_, B3, acc[4][3], 0, 0, 0); \
        acc[5][3] = __builtin_amdgcn_mfma_f32_16x16x32_bf16(a5_, B3, acc[5][3], 0, 0, 0); \
        acc[6][3] = __builtin_amdgcn_mfma_f32_16x16x32_bf16(a6_, B3, acc[6][3], 0, 0, 0); \
        acc[7][3] = __builtin_amdgcn_mfma_f32_16x16x32_bf16(a7_, B3, acc[7][3], 0, 0, 0); \
        __builtin_amdgcn_s_setprio(0); \
    } }
#define EPILOG \
    _Pragma("unroll") \
    for (int m = 0; m < 8; ++m) { \
        _Pragma("unroll") \
        for (int r = 0; r < 4; ++r) { \
            float F = acc[m][0][r], I = acc[m][1][r]; \
            float G = acc[m][2][r], O = acc[m][3][r]; \
            float c = fsigmoid(F) + fsigmoid(I) * ftanh(G); \
            float h = ftanh(c) * fsigmoid(O); \
            int row = row0 + m * 16 + lq * 4 + r; \
            int o   = row * 512 + colj; \
            out[o] = c; \
            out[33554432 + o] = h; \
        } }

    // ================= ci = 0: fused staging + K-loop =================
    {
        const int cn   = wv;                       // 16-col group
        const int colj = cn * 16 + l15;
        const char* bp = (const char*)Wp + (size_t)cn * 65536 + (size_t)lane * 16;

        float bias0 = bfv[colj], bias1 = biv[colj];
        float bias2 = bgv[colj], bias3 = bov[colj];
        f32x4 acc[8][4];
        #pragma unroll
        for (int m = 0; m < 8; ++m) {
            #pragma unroll
            for (int r = 0; r < 4; ++r) {
                acc[m][0][r] = bias0; acc[m][1][r] = bias1;
                acc[m][2][r] = bias2; acc[m][3][r] = bias3;
            }
        }

        f32x4 Ax0, Ax1, As0, As1;                  // staging set A (even slices)
        f32x4 Bx0, Bx1, Bs0, Bs1;                  // staging set B (odd slices)
        bf16x8 P0, P1, P2, P3;                     // B set even-ks
        bf16x8 Q0, Q1, Q2, Q3;                     // B set odd-ks

        asm volatile("s_waitcnt vmcnt(0)");        // bias loads drained
        __builtin_amdgcn_sched_barrier(0);
        STLD(Ax0, Ax1, As0, As1, 0)
        STLD(Bx0, Bx1, Bs0, Bs1, 1)
        LOADB(P0, P1, P2, P3, 0)

#define CSTEP(J, JP1, JP2, N0,N1,N2,N3, C0,C1,C2,C3, SX0,SX1,SS0,SS1) \
        LOADB(N0, N1, N2, N3, JP1) \
        WAITC(12) \
        STWR(SX0, SX1, SS0, SS1, J) \
        STLD(SX0, SX1, SS0, SS1, JP2) \
        WAITD(12) \
        DOMFMA(C0, C1, C2, C3, J)

        // j = 0 (d-wait 8)
        LOADB(Q0, Q1, Q2, Q3, 1)
        WAITC(12)
        STWR(Ax0, Ax1, As0, As1, 0)
        STLD(Ax0, Ax1, As0, As1, 2)
        WAITD(8)
        DOMFMA(P0, P1, P2, P3, 0)
        // j = 1..13 general
        CSTEP( 1,  2,  3, P0,P1,P2,P3, Q0,Q1,Q2,Q3, Bx0,Bx1,Bs0,Bs1)
        CSTEP( 2,  3,  4, Q0,Q1,Q2,Q3, P0,P1,P2,P3, Ax0,Ax1,As0,As1)
        CSTEP( 3,  4,  5, P0,P1,P2,P3, Q0,Q1,Q2,Q3, Bx0,Bx1,Bs0,Bs1)
        CSTEP( 4,  5,  6, Q0,Q1,Q2,Q3, P0,P1,P2,P3, Ax0,Ax1,As0,As1)
        CSTEP( 5,  6,  7, P0,P1,P2,P3, Q0,Q1,Q2,Q3, Bx0,Bx1,Bs0,Bs1)
        CSTEP( 6,  7,  8, Q0,Q1,Q2,Q3, P0,P1,P2,P3, Ax0,Ax1,As0,As1)
        CSTEP( 7,  8,  9, P0,P1,P2,P3, Q0,Q1,Q2,Q3, Bx0,Bx1,Bs0,Bs1)
        CSTEP( 8,  9, 10, Q0,Q1,Q2,Q3, P0,P1,P2,P3, Ax0,Ax1,As0,As1)
        CSTEP( 9, 10, 11, P0,P1,P2,P3, Q0,Q1,Q2,Q3, Bx0,Bx1,Bs0,Bs1)
        CSTEP(10, 11, 12, Q0,Q1,Q2,Q3, P0,P1,P2,P3, Ax0,Ax1,As0,As1)
        CSTEP(11, 12, 13, P0,P1,P2,P3, Q0,Q1,Q2,Q3, Bx0,Bx1,Bs0,Bs1)
        CSTEP(12, 13, 14, Q0,Q1,Q2,Q3, P0,P1,P2,P3, Ax0,Ax1,As0,As1)
        CSTEP(13, 14, 15, P0,P1,P2,P3, Q0,Q1,Q2,Q3, Bx0,Bx1,Bs0,Bs1)
        // j = 14 (no STLD; d-wait 8)
        LOADB(Q0, Q1, Q2, Q3, 15)
        WAITC(12)
        STWR(Ax0, Ax1, As0, As1, 14)
        WAITD(8)
        DOMFMA(P0, P1, P2, P3, 14)
        // j = 15 (no LOADB/STLD; c-wait 4, d-wait 0)
        WAITC(4)
        STWR(Bx0, Bx1, Bs0, Bs1, 15)
        WAITD(0)
        DOMFMA(Q0, Q1, Q2, Q3, 15)
#undef CSTEP

        EPILOG
    }

    // ================= ci = 1..3: r18 pipeline =================
    for (int ci = 1; ci < 4; ++ci) {
        const int cn   = ci * 8 + wv;
        const int colj = cn * 16 + l15;
        const char* bp = (const char*)Wp + (size_t)cn * 65536 + (size_t)lane * 16;

        float bias0 = bfv[colj], bias1 = biv[colj];
        float bias2 = bgv[colj], bias3 = bov[colj];
        f32x4 acc[8][4];
        #pragma unroll
        for (int m = 0; m < 8; ++m) {
            #pragma unroll
            for (int r = 0; r < 4; ++r) {
                acc[m][0][r] = bias0; acc[m][1][r] = bias1;
                acc[m][2][r] = bias2; acc[m][3][r] = bias3;
            }
        }

        bf16x8 P0, P1, P2, P3;
        bf16x8 Q0, Q1, Q2, Q3;

        asm volatile("s_waitcnt vmcnt(0)");
        __builtin_amdgcn_sched_barrier(0);
        LOADB(P0, P1, P2, P3, 0)
        #pragma unroll
        for (int ks = 0; ks < 16; ++ks) {
            if (ks < 15) {
                if ((ks + 1) & 1) { LOADB(Q0, Q1, Q2, Q3, ks + 1) }
                else              { LOADB(P0, P1, P2, P3, ks + 1) }
                WAITB4
            } else {
                WAITB0
            }
            if (ks & 1) { DOMFMA(Q0, Q1, Q2, Q3, ks) }
            else        { DOMFMA(P0, P1, P2, P3, ks) }
        }

        EPILOG
    }
#undef LOADB
#undef STLD
#undef STWR
#undef WAITC
#undef WAITD
#undef WAITB4
#undef WAITB0
#undef DOMFMA
#undef EPILOG
}

extern "C" void kernel_launch(void* const* d_in, const int* in_sizes, int n_in,
                              void* d_out, int out_size, void* d_ws, size_t ws_size,
                              hipStream_t stream) {
    const float* xin = (const float*)d_in[0];
    const float* stm = (const float*)d_in[1];
    const float* Wf  = (const float*)d_in[2];
    const float* bf_ = (const float*)d_in[3];
    const float* Wi  = (const float*)d_in[4];
    const float* bi_ = (const float*)d_in[5];
    const float* Wg  = (const float*)d_in[6];
    const float* bg_ = (const float*)d_in[7];
    const float* Wo  = (const float*)d_in[8];
    const float* bo_ = (const float*)d_in[9];
    __bf16* Wp = (__bf16*)d_ws;                    // 2 MiB packed weights

    wpack<<<512, 256, 0, stream>>>(Wf, Wi, Wg, Wo, Wp);
    lstm_main<<<512, 512, 0, stream>>>(xin, stm, Wp, bf_, bi_, bg_, bo_, (float*)d_out);
}